// Round 1
// baseline (951.387 us; speedup 1.0000x reference)
//
#include <hip/hip_runtime.h>
#include <hip/hip_bf16.h>
#include <math.h>

// Problem constants (from reference)
#define N_NODES   100000
#define N_EDGES   3200000
#define NODE_DIM  128
#define HID       16
#define N_GRAPHS  256

// ---------------------------------------------------------------------------
// Kernel 1: xw = x @ W   (x: [N,128], W: [128,16] -> xw: [N,16])
// 64 nodes per block, x tile staged in LDS (stride 129 to avoid bank
// conflicts), W fully staged (8 KB). Coalesced loads/stores.
// ---------------------------------------------------------------------------
__global__ __launch_bounds__(256) void xw_kernel(
    const float* __restrict__ x, const float* __restrict__ W,
    float* __restrict__ xw, int N)
{
    __shared__ float sW[NODE_DIM * HID];   // 8 KB
    __shared__ float sx[64 * 129];         // ~33 KB, padded stride
    const int t = threadIdx.x;

    #pragma unroll
    for (int i = 0; i < 8; ++i) sW[i * 256 + t] = W[i * 256 + t];

    const int base = blockIdx.x * 64;
    #pragma unroll
    for (int i = 0; i < 8; ++i) {
        int idx  = i * 256 + t;     // float4 index in tile (0..2047)
        int row  = idx >> 5;        // 32 float4 per row
        int col4 = idx & 31;
        float4 v = make_float4(0.f, 0.f, 0.f, 0.f);
        int n = base + row;
        if (n < N) v = ((const float4*)x)[(size_t)n * 32 + col4];
        float* d = &sx[row * 129 + col4 * 4];
        d[0] = v.x; d[1] = v.y; d[2] = v.z; d[3] = v.w;
    }
    __syncthreads();

    #pragma unroll
    for (int o = 0; o < 4; ++o) {
        int out_idx = o * 256 + t;
        int row = out_idx >> 4, dim = out_idx & 15;
        const float* xr = &sx[row * 129];
        float acc = 0.f;
        #pragma unroll 4
        for (int k = 0; k < NODE_DIM; ++k) acc += xr[k] * sW[k * HID + dim];
        int n = base + row;
        if (n < N) xw[(size_t)n * HID + dim] = acc;
    }
}

// ---------------------------------------------------------------------------
// Kernel 2: in-degree histogram over dst
// ---------------------------------------------------------------------------
__global__ void deg_kernel(const int* __restrict__ dst, int* __restrict__ deg, int E)
{
    int i = blockIdx.x * blockDim.x + threadIdx.x;
    if (i < E) atomicAdd(&deg[dst[i]], 1);
}

// ---------------------------------------------------------------------------
// Kernel 3: dinv = rsqrt(deg+1)   (+1 = self loop; always > 0)
// ---------------------------------------------------------------------------
__global__ void dinv_kernel(const int* __restrict__ deg, float* __restrict__ dinv, int N)
{
    int i = blockIdx.x * blockDim.x + threadIdx.x;
    if (i < N) dinv[i] = rsqrtf((float)(deg[i] + 1));
}

// ---------------------------------------------------------------------------
// Kernel 4: edge scatter: agg[dst] += dinv[src]*dinv[dst] * xw[src]
// 4 threads per edge, each handles 4 of the 16 dims (float4 gather).
// ---------------------------------------------------------------------------
__global__ __launch_bounds__(256) void edge_scatter_kernel(
    const int* __restrict__ src, const int* __restrict__ dst,
    const float* __restrict__ dinv, const float* __restrict__ xw,
    float* __restrict__ agg, int E)
{
    int tid = blockIdx.x * blockDim.x + threadIdx.x;
    int e = tid >> 2, sub = tid & 3;
    if (e >= E) return;
    int s = src[e], d = dst[e];
    float w = dinv[s] * dinv[d];
    float4 v = ((const float4*)xw)[(size_t)s * 4 + sub];
    float* p = agg + (size_t)d * HID + sub * 4;
    atomicAdd(p + 0, v.x * w);
    atomicAdd(p + 1, v.y * w);
    atomicAdd(p + 2, v.z * w);
    atomicAdd(p + 3, v.w * w);
}

// ---------------------------------------------------------------------------
// Kernel 5: g = relu(agg + dinv^2*xw + b); pool into per-graph sums/counts.
// batch is sorted -> a 64-node block spans very few graphs; accumulate into
// a full 256-graph LDS table, flush only the [gmin,gmax] range.
// ---------------------------------------------------------------------------
__global__ __launch_bounds__(256) void relu_pool_kernel(
    const float* __restrict__ agg, const float* __restrict__ xw,
    const float* __restrict__ dinv, const float* __restrict__ gcn_b,
    const int* __restrict__ batch,
    float* __restrict__ pool, float* __restrict__ cnt, int N)
{
    __shared__ float lpool[N_GRAPHS * HID];  // 16 KB
    __shared__ float lcnt[N_GRAPHS];
    const int t = threadIdx.x;
    for (int i = t; i < N_GRAPHS * HID; i += 256) lpool[i] = 0.f;
    if (t < N_GRAPHS) lcnt[t] = 0.f;
    __syncthreads();

    const int base = blockIdx.x * 64;
    const int n = base + (t >> 2), sub = t & 3;
    if (n < N) {
        int g = batch[n];
        float di = dinv[n];
        float selfw = di * di;
        float4 a  = ((const float4*)agg)[(size_t)n * 4 + sub];
        float4 v  = ((const float4*)xw)[(size_t)n * 4 + sub];
        float4 bb = ((const float4*)gcn_b)[sub];
        float r0 = fmaxf(a.x + selfw * v.x + bb.x, 0.f);
        float r1 = fmaxf(a.y + selfw * v.y + bb.y, 0.f);
        float r2 = fmaxf(a.z + selfw * v.z + bb.z, 0.f);
        float r3 = fmaxf(a.w + selfw * v.w + bb.w, 0.f);
        float* lp = &lpool[g * HID + sub * 4];
        atomicAdd(lp + 0, r0);
        atomicAdd(lp + 1, r1);
        atomicAdd(lp + 2, r2);
        atomicAdd(lp + 3, r3);
        if (sub == 0) atomicAdd(&lcnt[g], 1.f);
    }
    __syncthreads();

    if (base < N) {
        int last = min(base + 63, N - 1);
        int gmin = batch[base], gmax = batch[last];
        int range = gmax - gmin + 1;
        for (int i = t; i < range * HID; i += 256) {
            int g = gmin + (i >> 4), k = i & 15;
            float v = lpool[g * HID + k];
            if (v != 0.f) atomicAdd(&pool[g * HID + k], v);
        }
        for (int i = t; i < range; i += 256) {
            float c = lcnt[gmin + i];
            if (c != 0.f) atomicAdd(&cnt[gmin + i], c);
        }
    }
}

// ---------------------------------------------------------------------------
// Kernel 6: per-graph head. One wave (64 lanes) per graph.
// g_emb = pool/cnt; 4 modality FC+relu; concat(32); Linear(32,16)+relu;
// Linear(16,3); log_softmax.
// ---------------------------------------------------------------------------
__global__ __launch_bounds__(64) void head_kernel(
    const float* __restrict__ pool, const float* __restrict__ cnt,
    const float* __restrict__ mri,  const float* __restrict__ cog,
    const float* __restrict__ clin, const float* __restrict__ gen,
    const float* __restrict__ mriW, const float* __restrict__ mrib,
    const float* __restrict__ cogW, const float* __restrict__ cogb,
    const float* __restrict__ clinW, const float* __restrict__ clinb,
    const float* __restrict__ genW, const float* __restrict__ genb,
    const float* __restrict__ W1, const float* __restrict__ b1,
    const float* __restrict__ W2, const float* __restrict__ b2,
    float* __restrict__ out)
{
    const int g = blockIdx.x;
    const int lane = threadIdx.x;
    __shared__ float comb[32];
    __shared__ float h[HID];

    if (lane < HID) {
        float c = fmaxf(cnt[g], 1.f);
        comb[lane] = pool[g * HID + lane] / c;
    }

    // each modality: K-dim input -> 4 outputs, wave-parallel over K
    struct Mod { const float* in; const float* W; const float* b; int K; int off; };
    Mod mods[4] = {
        { mri  + (size_t)g * 256, mriW,  mrib,  256, 16 },
        { cog  + (size_t)g * 64,  cogW,  cogb,  64,  20 },
        { clin + (size_t)g * 32,  clinW, clinb, 32,  24 },
        { gen  + (size_t)g * 512, genW,  genb,  512, 28 },
    };
    for (int m = 0; m < 4; ++m) {
        float p0 = 0.f, p1 = 0.f, p2 = 0.f, p3 = 0.f;
        const float* in = mods[m].in;
        const float* Wm = mods[m].W;
        for (int k = lane; k < mods[m].K; k += 64) {
            float xv = in[k];
            p0 += xv * Wm[k * 4 + 0];
            p1 += xv * Wm[k * 4 + 1];
            p2 += xv * Wm[k * 4 + 2];
            p3 += xv * Wm[k * 4 + 3];
        }
        #pragma unroll
        for (int off = 32; off > 0; off >>= 1) {
            p0 += __shfl_down(p0, off);
            p1 += __shfl_down(p1, off);
            p2 += __shfl_down(p2, off);
            p3 += __shfl_down(p3, off);
        }
        if (lane == 0) {
            const float* bm = mods[m].b;
            int o = mods[m].off;
            comb[o + 0] = fmaxf(p0 + bm[0], 0.f);
            comb[o + 1] = fmaxf(p1 + bm[1], 0.f);
            comb[o + 2] = fmaxf(p2 + bm[2], 0.f);
            comb[o + 3] = fmaxf(p3 + bm[3], 0.f);
        }
    }
    __syncthreads();

    if (lane < HID) {
        float acc = b1[lane];
        #pragma unroll
        for (int k = 0; k < 32; ++k) acc += comb[k] * W1[k * HID + lane];
        h[lane] = fmaxf(acc, 0.f);
    }
    __syncthreads();

    if (lane == 0) {
        float l0 = b2[0], l1 = b2[1], l2 = b2[2];
        #pragma unroll
        for (int k = 0; k < HID; ++k) {
            float hv = h[k];
            l0 += hv * W2[k * 3 + 0];
            l1 += hv * W2[k * 3 + 1];
            l2 += hv * W2[k * 3 + 2];
        }
        float mx = fmaxf(l0, fmaxf(l1, l2));
        float lse = mx + logf(expf(l0 - mx) + expf(l1 - mx) + expf(l2 - mx));
        out[g * 3 + 0] = l0 - lse;
        out[g * 3 + 1] = l1 - lse;
        out[g * 3 + 2] = l2 - lse;
    }
}

// ---------------------------------------------------------------------------
// Launch
// ---------------------------------------------------------------------------
extern "C" void kernel_launch(void* const* d_in, const int* in_sizes, int n_in,
                              void* d_out, int out_size, void* d_ws, size_t ws_size,
                              hipStream_t stream)
{
    const float* x       = (const float*)d_in[0];
    const int*   eidx    = (const int*)d_in[1];      // [2, E] flattened, int32
    const int*   batch   = (const int*)d_in[2];
    const float* mri     = (const float*)d_in[3];
    const float* cog     = (const float*)d_in[4];
    const float* clin    = (const float*)d_in[5];
    const float* gen     = (const float*)d_in[6];
    const float* gcn_W   = (const float*)d_in[7];
    const float* gcn_b   = (const float*)d_in[8];
    const float* mriW    = (const float*)d_in[9];
    const float* mrib    = (const float*)d_in[10];
    const float* cogW    = (const float*)d_in[11];
    const float* cogb    = (const float*)d_in[12];
    const float* clinW   = (const float*)d_in[13];
    const float* clinb   = (const float*)d_in[14];
    const float* genW    = (const float*)d_in[15];
    const float* genb    = (const float*)d_in[16];
    const float* W1      = (const float*)d_in[17];
    const float* b1      = (const float*)d_in[18];
    const float* W2      = (const float*)d_in[19];
    const float* b2      = (const float*)d_in[20];
    float* out = (float*)d_out;

    const int N = in_sizes[0] / NODE_DIM;   // 100000
    const int E = in_sizes[1] / 2;          // 3200000
    const int* src = eidx;
    const int* dst = eidx + E;

    // workspace layout (floats)
    float* ws   = (float*)d_ws;
    float* xw   = ws;                          // N*16       = 1,600,000 f
    float* agg  = ws + 1600000;                // N*16       = 1,600,000 f
    int*   deg  = (int*)(ws + 3200000);        // N          =   100,000 i
    float* dinv = ws + 3300000;                // N          =   100,000 f
    float* pool = ws + 3400000;                // 256*16     =     4,096 f
    float* cnt  = ws + 3404096;                // 256        =       256 f

    // zero the accumulators (ws is poisoned 0xAA each call)
    hipMemsetAsync(agg,  0, (size_t)N * HID * sizeof(float), stream);
    hipMemsetAsync(deg,  0, (size_t)N * sizeof(int), stream);
    hipMemsetAsync(pool, 0, (N_GRAPHS * HID + N_GRAPHS) * sizeof(float), stream);

    xw_kernel<<<(N + 63) / 64, 256, 0, stream>>>(x, gcn_W, xw, N);
    deg_kernel<<<(E + 255) / 256, 256, 0, stream>>>(dst, deg, E);
    dinv_kernel<<<(N + 255) / 256, 256, 0, stream>>>(deg, dinv, N);
    edge_scatter_kernel<<<((size_t)E * 4 + 255) / 256, 256, 0, stream>>>(
        src, dst, dinv, xw, agg, E);
    relu_pool_kernel<<<(N + 63) / 64, 256, 0, stream>>>(
        agg, xw, dinv, gcn_b, batch, pool, cnt, N);
    head_kernel<<<N_GRAPHS, 64, 0, stream>>>(
        pool, cnt, mri, cog, clin, gen,
        mriW, mrib, cogW, cogb, clinW, clinb, genW, genb,
        W1, b1, W2, b2, out);
}

// Round 2
// 695.411 us; speedup vs baseline: 1.3681x; 1.3681x over previous
//
#include <hip/hip_runtime.h>
#include <hip/hip_bf16.h>
#include <math.h>

#define N_NODES   100000
#define N_EDGES   3200000
#define NODE_DIM  128
#define HID       16
#define N_GRAPHS  256

// ---------------------------------------------------------------------------
// Kernel 1: in-degree histogram over dst (real edges only; self-loop handled
// as +1 later).
// ---------------------------------------------------------------------------
__global__ void deg_kernel(const int* __restrict__ dst, int* __restrict__ deg, int E)
{
    int i = blockIdx.x * blockDim.x + threadIdx.x;
    if (i < E) atomicAdd(&deg[dst[i]], 1);
}

// ---------------------------------------------------------------------------
// Exclusive scan of deg -> off (and cursor copy). 1024 elems per block.
// ---------------------------------------------------------------------------
__global__ __launch_bounds__(256) void scan_blocksum(
    const int* __restrict__ deg, int* __restrict__ bsum, int N)
{
    __shared__ int red[256];
    int t = threadIdx.x;
    int base = blockIdx.x * 1024 + t * 4;
    int s = 0;
    #pragma unroll
    for (int k = 0; k < 4; ++k) { int i = base + k; if (i < N) s += deg[i]; }
    red[t] = s; __syncthreads();
    for (int o = 128; o > 0; o >>= 1) {
        if (t < o) red[t] += red[t + o];
        __syncthreads();
    }
    if (t == 0) bsum[blockIdx.x] = red[0];
}

__global__ __launch_bounds__(128) void scan_bsums(int* __restrict__ bsum, int nb)
{
    __shared__ int tmp[128];
    int t = threadIdx.x;
    int v = (t < nb) ? bsum[t] : 0;
    tmp[t] = v; __syncthreads();
    for (int o = 1; o < 128; o <<= 1) {
        int a = (t >= o) ? tmp[t - o] : 0;
        __syncthreads();
        tmp[t] += a;
        __syncthreads();
    }
    if (t < nb) bsum[t] = tmp[t] - v;   // exclusive
}

__global__ __launch_bounds__(256) void scan_write(
    const int* __restrict__ deg, const int* __restrict__ bsum,
    int* __restrict__ off, int* __restrict__ cursor, int N, int E)
{
    __shared__ int tsum[256];
    int t = threadIdx.x;
    int base = blockIdx.x * 1024 + t * 4;
    int v[4]; int s = 0;
    #pragma unroll
    for (int k = 0; k < 4; ++k) { int i = base + k; v[k] = (i < N) ? deg[i] : 0; s += v[k]; }
    tsum[t] = s; __syncthreads();
    int mine = s;
    for (int o = 1; o < 256; o <<= 1) {
        int a = (t >= o) ? tsum[t - o] : 0;
        __syncthreads();
        tsum[t] += a;
        __syncthreads();
    }
    int pre = bsum[blockIdx.x] + tsum[t] - mine;
    #pragma unroll
    for (int k = 0; k < 4; ++k) {
        int i = base + k;
        if (i < N) { off[i] = pre; cursor[i] = pre; pre += v[k]; }
    }
    if (blockIdx.x == 0 && t == 0) off[N] = E;
}

// ---------------------------------------------------------------------------
// dinv = rsqrt(deg+1)
// ---------------------------------------------------------------------------
__global__ void dinv_kernel(const int* __restrict__ deg, float* __restrict__ dinv, int N)
{
    int i = blockIdx.x * blockDim.x + threadIdx.x;
    if (i < N) dinv[i] = rsqrtf((float)(deg[i] + 1));
}

// ---------------------------------------------------------------------------
// CSR fill: slot = atomicAdd(cursor[dst]); csr[slot] = src
// ---------------------------------------------------------------------------
__global__ void fill_kernel(const int* __restrict__ src, const int* __restrict__ dst,
                            int* __restrict__ cursor, int* __restrict__ csr, int E)
{
    int i = blockIdx.x * blockDim.x + threadIdx.x;
    if (i < E) {
        int d = dst[i];
        int pos = atomicAdd(&cursor[d], 1);
        csr[pos] = src[i];
    }
}

// ---------------------------------------------------------------------------
// xws = dinv[n] * (x[n] @ W)   (x: [N,128], W: [128,16])
// ---------------------------------------------------------------------------
__global__ __launch_bounds__(256) void xw_kernel(
    const float* __restrict__ x, const float* __restrict__ W,
    const float* __restrict__ dinv, float* __restrict__ xws, int N)
{
    __shared__ float sW[NODE_DIM * HID];   // 8 KB
    __shared__ float sx[64 * 129];         // ~33 KB
    const int t = threadIdx.x;

    #pragma unroll
    for (int i = 0; i < 8; ++i) sW[i * 256 + t] = W[i * 256 + t];

    const int base = blockIdx.x * 64;
    #pragma unroll
    for (int i = 0; i < 8; ++i) {
        int idx  = i * 256 + t;
        int row  = idx >> 5;
        int col4 = idx & 31;
        float4 v = make_float4(0.f, 0.f, 0.f, 0.f);
        int n = base + row;
        if (n < N) v = ((const float4*)x)[(size_t)n * 32 + col4];
        float* d = &sx[row * 129 + col4 * 4];
        d[0] = v.x; d[1] = v.y; d[2] = v.z; d[3] = v.w;
    }
    __syncthreads();

    #pragma unroll
    for (int o = 0; o < 4; ++o) {
        int out_idx = o * 256 + t;
        int row = out_idx >> 4, dim = out_idx & 15;
        const float* xr = &sx[row * 129];
        float acc = 0.f;
        #pragma unroll 4
        for (int k = 0; k < NODE_DIM; ++k) acc += xr[k] * sW[k * HID + dim];
        int n = base + row;
        if (n < N) xws[(size_t)n * HID + dim] = acc * dinv[n];
    }
}

// ---------------------------------------------------------------------------
// Gather + ReLU + mean-pool. 16-lane subgroup per node-quad; 64 nodes/block.
// out[n][k] = relu(dinv[n] * (xws[n][k] + sum_{s in N(n)} xws[s][k]) + b[k])
// Pool into LDS range table (batch sorted), flush [gmin,gmax] only.
// ---------------------------------------------------------------------------
__global__ __launch_bounds__(256) void gather_pool_kernel(
    const int* __restrict__ off, const int* __restrict__ csr,
    const float* __restrict__ dinv, const float* __restrict__ xws,
    const float* __restrict__ gcn_b, const int* __restrict__ batch,
    float* __restrict__ pool, float* __restrict__ cnt, int N)
{
    __shared__ float lpool[N_GRAPHS * HID];  // used range only
    __shared__ float lcnt[N_GRAPHS];
    const int t = threadIdx.x;
    const int base = blockIdx.x * 64;
    const int last = min(base + 63, N - 1);
    const int gmin = batch[base], gmax = batch[last];
    const int range = gmax - gmin + 1;

    for (int i = t; i < range * HID; i += 256) lpool[i] = 0.f;
    for (int i = t; i < range; i += 256) lcnt[i] = 0.f;
    __syncthreads();

    const int sub = t >> 4, lane = t & 15;
    const float bb = gcn_b[lane];
    #pragma unroll
    for (int q = 0; q < 4; ++q) {
        int n = base + sub * 4 + q;
        if (n < N) {
            int s0 = off[n], s1 = off[n + 1];
            float acc = xws[(size_t)n * HID + lane];   // self-loop term
            for (int j = s0; j < s1; ++j) {
                int s = csr[j];
                acc += xws[(size_t)s * HID + lane];
            }
            float r = fmaxf(fmaf(dinv[n], acc, bb), 0.f);
            int g = batch[n] - gmin;
            atomicAdd(&lpool[g * HID + lane], r);
            if (lane == 0) atomicAdd(&lcnt[g], 1.f);
        }
    }
    __syncthreads();

    for (int i = t; i < range * HID; i += 256) {
        float v = lpool[i];
        if (v != 0.f) atomicAdd(&pool[gmin * HID + i], v);
    }
    for (int i = t; i < range; i += 256) {
        float c = lcnt[i];
        if (c != 0.f) atomicAdd(&cnt[gmin + i], c);
    }
}

// ---------------------------------------------------------------------------
// Per-graph head: one wave per graph.
// ---------------------------------------------------------------------------
__global__ __launch_bounds__(64) void head_kernel(
    const float* __restrict__ pool, const float* __restrict__ cnt,
    const float* __restrict__ mri,  const float* __restrict__ cog,
    const float* __restrict__ clin, const float* __restrict__ gen,
    const float* __restrict__ mriW, const float* __restrict__ mrib,
    const float* __restrict__ cogW, const float* __restrict__ cogb,
    const float* __restrict__ clinW, const float* __restrict__ clinb,
    const float* __restrict__ genW, const float* __restrict__ genb,
    const float* __restrict__ W1, const float* __restrict__ b1,
    const float* __restrict__ W2, const float* __restrict__ b2,
    float* __restrict__ out)
{
    const int g = blockIdx.x;
    const int lane = threadIdx.x;
    __shared__ float comb[32];
    __shared__ float h[HID];

    if (lane < HID) {
        float c = fmaxf(cnt[g], 1.f);
        comb[lane] = pool[g * HID + lane] / c;
    }

    struct Mod { const float* in; const float* W; const float* b; int K; int off; };
    Mod mods[4] = {
        { mri  + (size_t)g * 256, mriW,  mrib,  256, 16 },
        { cog  + (size_t)g * 64,  cogW,  cogb,  64,  20 },
        { clin + (size_t)g * 32,  clinW, clinb, 32,  24 },
        { gen  + (size_t)g * 512, genW,  genb,  512, 28 },
    };
    for (int m = 0; m < 4; ++m) {
        float p0 = 0.f, p1 = 0.f, p2 = 0.f, p3 = 0.f;
        const float* in = mods[m].in;
        const float* Wm = mods[m].W;
        for (int k = lane; k < mods[m].K; k += 64) {
            float xv = in[k];
            p0 += xv * Wm[k * 4 + 0];
            p1 += xv * Wm[k * 4 + 1];
            p2 += xv * Wm[k * 4 + 2];
            p3 += xv * Wm[k * 4 + 3];
        }
        #pragma unroll
        for (int o = 32; o > 0; o >>= 1) {
            p0 += __shfl_down(p0, o);
            p1 += __shfl_down(p1, o);
            p2 += __shfl_down(p2, o);
            p3 += __shfl_down(p3, o);
        }
        if (lane == 0) {
            const float* bm = mods[m].b;
            int o = mods[m].off;
            comb[o + 0] = fmaxf(p0 + bm[0], 0.f);
            comb[o + 1] = fmaxf(p1 + bm[1], 0.f);
            comb[o + 2] = fmaxf(p2 + bm[2], 0.f);
            comb[o + 3] = fmaxf(p3 + bm[3], 0.f);
        }
    }
    __syncthreads();

    if (lane < HID) {
        float acc = b1[lane];
        #pragma unroll
        for (int k = 0; k < 32; ++k) acc += comb[k] * W1[k * HID + lane];
        h[lane] = fmaxf(acc, 0.f);
    }
    __syncthreads();

    if (lane == 0) {
        float l0 = b2[0], l1 = b2[1], l2 = b2[2];
        #pragma unroll
        for (int k = 0; k < HID; ++k) {
            float hv = h[k];
            l0 += hv * W2[k * 3 + 0];
            l1 += hv * W2[k * 3 + 1];
            l2 += hv * W2[k * 3 + 2];
        }
        float mx = fmaxf(l0, fmaxf(l1, l2));
        float lse = mx + logf(expf(l0 - mx) + expf(l1 - mx) + expf(l2 - mx));
        out[g * 3 + 0] = l0 - lse;
        out[g * 3 + 1] = l1 - lse;
        out[g * 3 + 2] = l2 - lse;
    }
}

// ---------------------------------------------------------------------------
// Launch
// ---------------------------------------------------------------------------
extern "C" void kernel_launch(void* const* d_in, const int* in_sizes, int n_in,
                              void* d_out, int out_size, void* d_ws, size_t ws_size,
                              hipStream_t stream)
{
    const float* x     = (const float*)d_in[0];
    const int*   eidx  = (const int*)d_in[1];
    const int*   batch = (const int*)d_in[2];
    const float* mri   = (const float*)d_in[3];
    const float* cog   = (const float*)d_in[4];
    const float* clin  = (const float*)d_in[5];
    const float* gen   = (const float*)d_in[6];
    const float* gcn_W = (const float*)d_in[7];
    const float* gcn_b = (const float*)d_in[8];
    const float* mriW  = (const float*)d_in[9];
    const float* mrib  = (const float*)d_in[10];
    const float* cogW  = (const float*)d_in[11];
    const float* cogb  = (const float*)d_in[12];
    const float* clinW = (const float*)d_in[13];
    const float* clinb = (const float*)d_in[14];
    const float* genW  = (const float*)d_in[15];
    const float* genb  = (const float*)d_in[16];
    const float* W1    = (const float*)d_in[17];
    const float* b1    = (const float*)d_in[18];
    const float* W2    = (const float*)d_in[19];
    const float* b2    = (const float*)d_in[20];
    float* out = (float*)d_out;

    const int N = in_sizes[0] / NODE_DIM;   // 100000
    const int E = in_sizes[1] / 2;          // 3200000
    const int* src = eidx;
    const int* dst = eidx + E;

    // workspace layout (float-sized slots)
    float* ws     = (float*)d_ws;
    float* xws    = ws;                      // 1,600,000 f
    float* dinv   = ws + 1600000;            //   100,000 f
    float* pool   = ws + 1700000;            //     4,096 f
    float* cnt    = ws + 1704096;            //       256 f
    int*   deg    = (int*)(ws + 1705000);    //   100,000 i
    int*   off    = (int*)(ws + 1805000);    //   100,001 i
    int*   cursor = (int*)(ws + 1906000);    //   100,000 i
    int*   bsum   = (int*)(ws + 2006000);    //       128 i
    int*   csr    = (int*)(ws + 2006500);    // 3,200,000 i
    // total ~5.21M * 4B = ~20.8 MB

    const int NB = (N + 1023) / 1024;       // 98 scan blocks

    hipMemsetAsync(deg,  0, (size_t)N * sizeof(int), stream);
    hipMemsetAsync(pool, 0, (N_GRAPHS * HID + N_GRAPHS) * sizeof(float), stream);

    deg_kernel<<<(E + 255) / 256, 256, 0, stream>>>(dst, deg, E);
    scan_blocksum<<<NB, 256, 0, stream>>>(deg, bsum, N);
    scan_bsums<<<1, 128, 0, stream>>>(bsum, NB);
    scan_write<<<NB, 256, 0, stream>>>(deg, bsum, off, cursor, N, E);
    dinv_kernel<<<(N + 255) / 256, 256, 0, stream>>>(deg, dinv, N);
    fill_kernel<<<(E + 255) / 256, 256, 0, stream>>>(src, dst, cursor, csr, E);
    xw_kernel<<<(N + 63) / 64, 256, 0, stream>>>(x, gcn_W, dinv, xws, N);
    gather_pool_kernel<<<(N + 63) / 64, 256, 0, stream>>>(
        off, csr, dinv, xws, gcn_b, batch, pool, cnt, N);
    head_kernel<<<N_GRAPHS, 64, 0, stream>>>(
        pool, cnt, mri, cog, clin, gen,
        mriW, mrib, cogW, cogb, clinW, clinb, genW, genb,
        W1, b1, W2, b2, out);
}

// Round 3
// 578.508 us; speedup vs baseline: 1.6446x; 1.2021x over previous
//
#include <hip/hip_runtime.h>
#include <hip/hip_bf16.h>
#include <math.h>

#define N_NODES   100000
#define N_EDGES   3200000
#define NODE_DIM  128
#define HID       16
#define N_GRAPHS  256

// Bucketing: 128 nodes per bucket
#define BSHIFT    7
#define NPB       128                          // nodes per bucket
#define NBUCK     ((N_NODES + NPB - 1) >> BSHIFT)   // 782
#define NBLK      256                          // blocks in count/scatter passes
#define TOT       (NBUCK * NBLK)               // 200192 count entries

// ---------------------------------------------------------------------------
// Pass A: per-block bucket histogram. M[k*NBLK + b] = #edges in block b's
// chunk with dst in bucket k. LDS atomics only.
// ---------------------------------------------------------------------------
__global__ __launch_bounds__(256) void bucket_count(
    const int* __restrict__ dst, int* __restrict__ M, int E, int chunk)
{
    __shared__ int cnt[NBUCK];
    const int t = threadIdx.x, b = blockIdx.x;
    for (int k = t; k < NBUCK; k += 256) cnt[k] = 0;
    __syncthreads();
    int e0 = b * chunk, e1 = min(E, e0 + chunk);
    for (int e = e0 + t; e < e1; e += 256) atomicAdd(&cnt[dst[e] >> BSHIFT], 1);
    __syncthreads();
    for (int k = t; k < NBUCK; k += 256) M[k * NBLK + b] = cnt[k];
}

// ---------------------------------------------------------------------------
// Exclusive scan of M[0..TOT) in place (3-kernel hierarchical scan).
// ---------------------------------------------------------------------------
__global__ __launch_bounds__(256) void scan_blocksum(
    const int* __restrict__ M, int* __restrict__ bsum, int n)
{
    __shared__ int red[256];
    int t = threadIdx.x;
    int base = blockIdx.x * 1024 + t * 4;
    int s = 0;
    #pragma unroll
    for (int k = 0; k < 4; ++k) { int i = base + k; if (i < n) s += M[i]; }
    red[t] = s; __syncthreads();
    for (int o = 128; o > 0; o >>= 1) {
        if (t < o) red[t] += red[t + o];
        __syncthreads();
    }
    if (t == 0) bsum[blockIdx.x] = red[0];
}

__global__ __launch_bounds__(256) void scan_bsums(int* __restrict__ bsum, int nb)
{
    __shared__ int tmp[256];
    int t = threadIdx.x;
    int v = (t < nb) ? bsum[t] : 0;
    tmp[t] = v; __syncthreads();
    for (int o = 1; o < 256; o <<= 1) {
        int a = (t >= o) ? tmp[t - o] : 0;
        __syncthreads();
        tmp[t] += a;
        __syncthreads();
    }
    if (t < nb) bsum[t] = tmp[t] - v;   // exclusive
}

__global__ __launch_bounds__(256) void scan_write(
    int* __restrict__ M, const int* __restrict__ bsum, int n)
{
    __shared__ int tsum[256];
    int t = threadIdx.x;
    int base = blockIdx.x * 1024 + t * 4;
    int v[4]; int s = 0;
    #pragma unroll
    for (int k = 0; k < 4; ++k) { int i = base + k; v[k] = (i < n) ? M[i] : 0; s += v[k]; }
    tsum[t] = s; __syncthreads();
    int mine = s;
    for (int o = 1; o < 256; o <<= 1) {
        int a = (t >= o) ? tsum[t - o] : 0;
        __syncthreads();
        tsum[t] += a;
        __syncthreads();
    }
    int pre = bsum[blockIdx.x] + tsum[t] - mine;
    #pragma unroll
    for (int k = 0; k < 4; ++k) {
        int i = base + k;
        if (i < n) { M[i] = pre; pre += v[k]; }
    }
}

// ---------------------------------------------------------------------------
// Pass C: bin edges by dst bucket. Each (block,bucket) region is contiguous
// (avg 16 edges = 64 B run). Payload packed: src | (dloc << 17).
// ---------------------------------------------------------------------------
__global__ __launch_bounds__(256) void bucket_scatter(
    const int* __restrict__ src, const int* __restrict__ dst,
    const int* __restrict__ gOff, int* __restrict__ ebuf, int E, int chunk)
{
    __shared__ int cur[NBUCK];
    const int t = threadIdx.x, b = blockIdx.x;
    for (int k = t; k < NBUCK; k += 256) cur[k] = gOff[k * NBLK + b];
    __syncthreads();
    int e0 = b * chunk, e1 = min(E, e0 + chunk);
    for (int e = e0 + t; e < e1; e += 256) {
        int d = dst[e], s = src[e];
        int pos = atomicAdd(&cur[d >> BSHIFT], 1);
        ebuf[pos] = s | ((d & (NPB - 1)) << 17);
    }
}

// ---------------------------------------------------------------------------
// Per-bucket degree histogram -> dinv (LDS atomics, coalesced write).
// ---------------------------------------------------------------------------
__global__ __launch_bounds__(256) void deg_dinv(
    const int* __restrict__ gOff, const int* __restrict__ ebuf,
    float* __restrict__ dinv, int E, int N)
{
    __shared__ int hist[NPB];
    const int k = blockIdx.x, t = threadIdx.x;
    if (t < NPB) hist[t] = 0;
    __syncthreads();
    int e0 = gOff[k * NBLK];
    int e1 = (k + 1 < NBUCK) ? gOff[(k + 1) * NBLK] : E;
    for (int e = e0 + t; e < e1; e += 256) atomicAdd(&hist[ebuf[e] >> 17], 1);
    __syncthreads();
    int n = (k << BSHIFT) + t;
    if (t < NPB && n < N) dinv[n] = rsqrtf((float)(hist[t] + 1));
}

// ---------------------------------------------------------------------------
// xws = dinv[n] * (x[n] @ W)
// ---------------------------------------------------------------------------
__global__ __launch_bounds__(256) void xw_kernel(
    const float* __restrict__ x, const float* __restrict__ W,
    const float* __restrict__ dinv, float* __restrict__ xws, int N)
{
    __shared__ float sW[NODE_DIM * HID];   // 8 KB
    __shared__ float sx[64 * 129];         // ~33 KB
    const int t = threadIdx.x;

    #pragma unroll
    for (int i = 0; i < 8; ++i) sW[i * 256 + t] = W[i * 256 + t];

    const int base = blockIdx.x * 64;
    #pragma unroll
    for (int i = 0; i < 8; ++i) {
        int idx  = i * 256 + t;
        int row  = idx >> 5;
        int col4 = idx & 31;
        float4 v = make_float4(0.f, 0.f, 0.f, 0.f);
        int n = base + row;
        if (n < N) v = ((const float4*)x)[(size_t)n * 32 + col4];
        float* d = &sx[row * 129 + col4 * 4];
        d[0] = v.x; d[1] = v.y; d[2] = v.z; d[3] = v.w;
    }
    __syncthreads();

    #pragma unroll
    for (int o = 0; o < 4; ++o) {
        int out_idx = o * 256 + t;
        int row = out_idx >> 4, dim = out_idx & 15;
        const float* xr = &sx[row * 129];
        float acc = 0.f;
        #pragma unroll 4
        for (int k = 0; k < NODE_DIM; ++k) acc += xr[k] * sW[k * HID + dim];
        int n = base + row;
        if (n < N) xws[(size_t)n * HID + dim] = acc * dinv[n];
    }
}

// ---------------------------------------------------------------------------
// Per-bucket gather + self-loop + ReLU + mean-pool. LDS fp32 accumulation
// (ds_add_f32), no global float atomics for aggregation. 16 lanes per edge.
// ---------------------------------------------------------------------------
__global__ __launch_bounds__(256) void gather_pool(
    const int* __restrict__ gOff, const int* __restrict__ ebuf,
    const float* __restrict__ dinv, const float* __restrict__ xws,
    const float* __restrict__ gcn_b, const int* __restrict__ batch,
    float* __restrict__ pool, float* __restrict__ cnt, int E, int N)
{
    __shared__ float acc[NPB * HID];     // 8 KB
    __shared__ float lpool[16 * HID];    // 1 KB
    __shared__ float lcnt[16];
    const int k = blockIdx.x, t = threadIdx.x;
    const int base = k << BSHIFT;

    for (int i = t; i < NPB * HID; i += 256) acc[i] = 0.f;
    if (t < 16 * HID) lpool[t] = 0.f;
    if (t < 16) lcnt[t] = 0.f;
    __syncthreads();

    int e0 = gOff[k * NBLK];
    int e1 = (k + 1 < NBUCK) ? gOff[(k + 1) * NBLK] : E;
    const int sub = t >> 4, lane = t & 15;

    #pragma unroll 4
    for (int e = e0 + sub; e < e1; e += 16) {
        int w = ebuf[e];
        int s = w & 0x1FFFF;
        int dloc = w >> 17;
        float v = xws[(size_t)s * HID + lane];
        atomicAdd(&acc[dloc * HID + lane], v);
    }
    __syncthreads();

    int nN = min(NPB, N - base);
    int gmin = batch[base], gmax = batch[base + nN - 1];
    int range = gmax - gmin + 1;
    bool useL = (range <= 16);
    float bb = gcn_b[lane];

    for (int i = sub; i < nN; i += 16) {
        int n = base + i;
        float a = acc[i * HID + lane] + xws[(size_t)n * HID + lane];
        float r = fmaxf(fmaf(dinv[n], a, bb), 0.f);
        int g = batch[n];
        if (useL) {
            atomicAdd(&lpool[(g - gmin) * HID + lane], r);
            if (lane == 0) atomicAdd(&lcnt[g - gmin], 1.f);
        } else {
            atomicAdd(&pool[g * HID + lane], r);
            if (lane == 0) atomicAdd(&cnt[g], 1.f);
        }
    }
    __syncthreads();

    if (useL) {
        for (int i = t; i < range * HID; i += 256) {
            float v = lpool[i];
            if (v != 0.f) atomicAdd(&pool[gmin * HID + i], v);
        }
        for (int i = t; i < range; i += 256) {
            float c = lcnt[i];
            if (c != 0.f) atomicAdd(&cnt[gmin + i], c);
        }
    }
}

// ---------------------------------------------------------------------------
// Per-graph head: one wave per graph.
// ---------------------------------------------------------------------------
__global__ __launch_bounds__(64) void head_kernel(
    const float* __restrict__ pool, const float* __restrict__ cnt,
    const float* __restrict__ mri,  const float* __restrict__ cog,
    const float* __restrict__ clin, const float* __restrict__ gen,
    const float* __restrict__ mriW, const float* __restrict__ mrib,
    const float* __restrict__ cogW, const float* __restrict__ cogb,
    const float* __restrict__ clinW, const float* __restrict__ clinb,
    const float* __restrict__ genW, const float* __restrict__ genb,
    const float* __restrict__ W1, const float* __restrict__ b1,
    const float* __restrict__ W2, const float* __restrict__ b2,
    float* __restrict__ out)
{
    const int g = blockIdx.x;
    const int lane = threadIdx.x;
    __shared__ float comb[32];
    __shared__ float h[HID];

    if (lane < HID) {
        float c = fmaxf(cnt[g], 1.f);
        comb[lane] = pool[g * HID + lane] / c;
    }

    struct Mod { const float* in; const float* W; const float* b; int K; int off; };
    Mod mods[4] = {
        { mri  + (size_t)g * 256, mriW,  mrib,  256, 16 },
        { cog  + (size_t)g * 64,  cogW,  cogb,  64,  20 },
        { clin + (size_t)g * 32,  clinW, clinb, 32,  24 },
        { gen  + (size_t)g * 512, genW,  genb,  512, 28 },
    };
    for (int m = 0; m < 4; ++m) {
        float p0 = 0.f, p1 = 0.f, p2 = 0.f, p3 = 0.f;
        const float* in = mods[m].in;
        const float* Wm = mods[m].W;
        for (int kk = lane; kk < mods[m].K; kk += 64) {
            float xv = in[kk];
            p0 += xv * Wm[kk * 4 + 0];
            p1 += xv * Wm[kk * 4 + 1];
            p2 += xv * Wm[kk * 4 + 2];
            p3 += xv * Wm[kk * 4 + 3];
        }
        #pragma unroll
        for (int o = 32; o > 0; o >>= 1) {
            p0 += __shfl_down(p0, o);
            p1 += __shfl_down(p1, o);
            p2 += __shfl_down(p2, o);
            p3 += __shfl_down(p3, o);
        }
        if (lane == 0) {
            const float* bm = mods[m].b;
            int o = mods[m].off;
            comb[o + 0] = fmaxf(p0 + bm[0], 0.f);
            comb[o + 1] = fmaxf(p1 + bm[1], 0.f);
            comb[o + 2] = fmaxf(p2 + bm[2], 0.f);
            comb[o + 3] = fmaxf(p3 + bm[3], 0.f);
        }
    }
    __syncthreads();

    if (lane < HID) {
        float a = b1[lane];
        #pragma unroll
        for (int kk = 0; kk < 32; ++kk) a += comb[kk] * W1[kk * HID + lane];
        h[lane] = fmaxf(a, 0.f);
    }
    __syncthreads();

    if (lane == 0) {
        float l0 = b2[0], l1 = b2[1], l2 = b2[2];
        #pragma unroll
        for (int kk = 0; kk < HID; ++kk) {
            float hv = h[kk];
            l0 += hv * W2[kk * 3 + 0];
            l1 += hv * W2[kk * 3 + 1];
            l2 += hv * W2[kk * 3 + 2];
        }
        float mx = fmaxf(l0, fmaxf(l1, l2));
        float lse = mx + logf(expf(l0 - mx) + expf(l1 - mx) + expf(l2 - mx));
        out[g * 3 + 0] = l0 - lse;
        out[g * 3 + 1] = l1 - lse;
        out[g * 3 + 2] = l2 - lse;
    }
}

// ---------------------------------------------------------------------------
// Launch
// ---------------------------------------------------------------------------
extern "C" void kernel_launch(void* const* d_in, const int* in_sizes, int n_in,
                              void* d_out, int out_size, void* d_ws, size_t ws_size,
                              hipStream_t stream)
{
    const float* x     = (const float*)d_in[0];
    const int*   eidx  = (const int*)d_in[1];
    const int*   batch = (const int*)d_in[2];
    const float* mri   = (const float*)d_in[3];
    const float* cog   = (const float*)d_in[4];
    const float* clin  = (const float*)d_in[5];
    const float* gen   = (const float*)d_in[6];
    const float* gcn_W = (const float*)d_in[7];
    const float* gcn_b = (const float*)d_in[8];
    const float* mriW  = (const float*)d_in[9];
    const float* mrib  = (const float*)d_in[10];
    const float* cogW  = (const float*)d_in[11];
    const float* cogb  = (const float*)d_in[12];
    const float* clinW = (const float*)d_in[13];
    const float* clinb = (const float*)d_in[14];
    const float* genW  = (const float*)d_in[15];
    const float* genb  = (const float*)d_in[16];
    const float* W1    = (const float*)d_in[17];
    const float* b1    = (const float*)d_in[18];
    const float* W2    = (const float*)d_in[19];
    const float* b2    = (const float*)d_in[20];
    float* out = (float*)d_out;

    const int N = in_sizes[0] / NODE_DIM;   // 100000
    const int E = in_sizes[1] / 2;          // 3200000
    const int* src = eidx;
    const int* dst = eidx + E;

    // workspace layout (4-byte units)
    float* ws   = (float*)d_ws;
    float* xws  = ws;                        // 1,600,000 f
    float* dinv = ws + 1600000;              //   100,000 f
    float* pool = ws + 1700000;              //     4,096 f
    float* cnt  = ws + 1704096;              //       256 f
    int*   M    = (int*)(ws + 1705000);      //   200,192 i (counts -> offsets, scanned in place)
    int*   bsum = (int*)(ws + 1906000);      //       256 i
    int*   ebuf = (int*)(ws + 1907000);      // 3,200,000 i
    // total ~5.11M * 4B = ~20.4 MB

    const int chunkE = (E + NBLK - 1) / NBLK;       // 12500
    const int scanNB = (TOT + 1023) / 1024;         // 196

    hipMemsetAsync(pool, 0, (N_GRAPHS * HID + N_GRAPHS) * sizeof(float), stream);

    bucket_count<<<NBLK, 256, 0, stream>>>(dst, M, E, chunkE);
    scan_blocksum<<<scanNB, 256, 0, stream>>>(M, bsum, TOT);
    scan_bsums<<<1, 256, 0, stream>>>(bsum, scanNB);
    scan_write<<<scanNB, 256, 0, stream>>>(M, bsum, TOT);
    bucket_scatter<<<NBLK, 256, 0, stream>>>(src, dst, M, ebuf, E, chunkE);
    deg_dinv<<<NBUCK, 256, 0, stream>>>(M, ebuf, dinv, E, N);
    xw_kernel<<<(N + 63) / 64, 256, 0, stream>>>(x, gcn_W, dinv, xws, N);
    gather_pool<<<NBUCK, 256, 0, stream>>>(M, ebuf, dinv, xws, gcn_b, batch,
                                           pool, cnt, E, N);
    head_kernel<<<N_GRAPHS, 64, 0, stream>>>(
        pool, cnt, mri, cog, clin, gen,
        mriW, mrib, cogW, cogb, clinW, clinb, genW, genb,
        W1, b1, W2, b2, out);
}

// Round 4
// 544.009 us; speedup vs baseline: 1.7488x; 1.0634x over previous
//
#include <hip/hip_runtime.h>
#include <hip/hip_bf16.h>
#include <math.h>

#define N_NODES   100000
#define N_EDGES   3200000
#define NODE_DIM  128
#define HID       16
#define N_GRAPHS  256

// Bucketing: 64 nodes per bucket
#define BSHIFT    6
#define NPB       64                                // nodes per bucket
#define NBUCK     ((N_NODES + NPB - 1) >> BSHIFT)   // 1563
#define NBLK      256                               // blocks in count/scatter
#define TOT       (NBUCK * NBLK)                    // 400128 count entries

// ---------------------------------------------------------------------------
// Pass A: per-block bucket histogram (LDS atomics only).
// ---------------------------------------------------------------------------
__global__ __launch_bounds__(256) void bucket_count(
    const int* __restrict__ dst, int* __restrict__ M, int E, int chunk)
{
    __shared__ int cnt[NBUCK];
    const int t = threadIdx.x, b = blockIdx.x;
    for (int k = t; k < NBUCK; k += 256) cnt[k] = 0;
    __syncthreads();
    int e0 = b * chunk, e1 = min(E, e0 + chunk);
    if (((e0 | e1) & 3) == 0) {
        const int4* d4 = (const int4*)dst;
        for (int i = (e0 >> 2) + t; i < (e1 >> 2); i += 256) {
            int4 d = d4[i];
            atomicAdd(&cnt[d.x >> BSHIFT], 1);
            atomicAdd(&cnt[d.y >> BSHIFT], 1);
            atomicAdd(&cnt[d.z >> BSHIFT], 1);
            atomicAdd(&cnt[d.w >> BSHIFT], 1);
        }
    } else {
        for (int e = e0 + t; e < e1; e += 256) atomicAdd(&cnt[dst[e] >> BSHIFT], 1);
    }
    __syncthreads();
    for (int k = t; k < NBUCK; k += 256) M[k * NBLK + b] = cnt[k];
}

// ---------------------------------------------------------------------------
// Hierarchical exclusive scan of M[0..TOT), 2048 elems per block.
// ---------------------------------------------------------------------------
__global__ __launch_bounds__(256) void scan_blocksum(
    const int* __restrict__ M, int* __restrict__ bsum, int n)
{
    __shared__ int red[256];
    int t = threadIdx.x;
    int base = blockIdx.x * 2048 + t * 8;
    int s = 0;
    #pragma unroll
    for (int k = 0; k < 8; ++k) { int i = base + k; if (i < n) s += M[i]; }
    red[t] = s; __syncthreads();
    for (int o = 128; o > 0; o >>= 1) {
        if (t < o) red[t] += red[t + o];
        __syncthreads();
    }
    if (t == 0) bsum[blockIdx.x] = red[0];
}

__global__ __launch_bounds__(256) void scan_bsums(int* __restrict__ bsum, int nb)
{
    __shared__ int tmp[256];
    int t = threadIdx.x;
    int v = (t < nb) ? bsum[t] : 0;
    tmp[t] = v; __syncthreads();
    for (int o = 1; o < 256; o <<= 1) {
        int a = (t >= o) ? tmp[t - o] : 0;
        __syncthreads();
        tmp[t] += a;
        __syncthreads();
    }
    if (t < nb) bsum[t] = tmp[t] - v;   // exclusive
}

__global__ __launch_bounds__(256) void scan_write(
    int* __restrict__ M, const int* __restrict__ bsum, int n)
{
    __shared__ int tsum[256];
    int t = threadIdx.x;
    int base = blockIdx.x * 2048 + t * 8;
    int v[8]; int s = 0;
    #pragma unroll
    for (int k = 0; k < 8; ++k) { int i = base + k; v[k] = (i < n) ? M[i] : 0; s += v[k]; }
    tsum[t] = s; __syncthreads();
    int mine = s;
    for (int o = 1; o < 256; o <<= 1) {
        int a = (t >= o) ? tsum[t - o] : 0;
        __syncthreads();
        tsum[t] += a;
        __syncthreads();
    }
    int pre = bsum[blockIdx.x] + tsum[t] - mine;
    #pragma unroll
    for (int k = 0; k < 8; ++k) {
        int i = base + k;
        if (i < n) { M[i] = pre; pre += v[k]; }
    }
}

// ---------------------------------------------------------------------------
// Pass C: bin edges by dst bucket. Payload packed: src | (dloc << 17).
// ---------------------------------------------------------------------------
__global__ __launch_bounds__(256) void bucket_scatter(
    const int* __restrict__ src, const int* __restrict__ dst,
    const int* __restrict__ gOff, int* __restrict__ ebuf, int E, int chunk)
{
    __shared__ int cur[NBUCK];
    const int t = threadIdx.x, b = blockIdx.x;
    for (int k = t; k < NBUCK; k += 256) cur[k] = gOff[k * NBLK + b];
    __syncthreads();
    int e0 = b * chunk, e1 = min(E, e0 + chunk);
    if (((e0 | e1) & 3) == 0) {
        const int4* d4 = (const int4*)dst;
        const int4* s4 = (const int4*)src;
        for (int i = (e0 >> 2) + t; i < (e1 >> 2); i += 256) {
            int4 d = d4[i];
            int4 s = s4[i];
            int p;
            p = atomicAdd(&cur[d.x >> BSHIFT], 1); ebuf[p] = s.x | ((d.x & (NPB-1)) << 17);
            p = atomicAdd(&cur[d.y >> BSHIFT], 1); ebuf[p] = s.y | ((d.y & (NPB-1)) << 17);
            p = atomicAdd(&cur[d.z >> BSHIFT], 1); ebuf[p] = s.z | ((d.z & (NPB-1)) << 17);
            p = atomicAdd(&cur[d.w >> BSHIFT], 1); ebuf[p] = s.w | ((d.w & (NPB-1)) << 17);
        }
    } else {
        for (int e = e0 + t; e < e1; e += 256) {
            int d = dst[e];
            int p = atomicAdd(&cur[d >> BSHIFT], 1);
            ebuf[p] = src[e] | ((d & (NPB-1)) << 17);
        }
    }
}

// ---------------------------------------------------------------------------
// Per-bucket degree histogram -> dinv.
// ---------------------------------------------------------------------------
__global__ __launch_bounds__(256) void deg_dinv(
    const int* __restrict__ gOff, const int* __restrict__ ebuf,
    float* __restrict__ dinv, int E, int N)
{
    __shared__ int hist[NPB];
    const int k = blockIdx.x, t = threadIdx.x;
    if (t < NPB) hist[t] = 0;
    __syncthreads();
    int e0 = gOff[k * NBLK];
    int e1 = (k + 1 < NBUCK) ? gOff[(k + 1) * NBLK] : E;
    for (int e = e0 + t; e < e1; e += 256) atomicAdd(&hist[ebuf[e] >> 17], 1);
    __syncthreads();
    int n = (k << BSHIFT) + t;
    if (t < NPB && n < N) dinv[n] = rsqrtf((float)(hist[t] + 1));
}

// ---------------------------------------------------------------------------
// xws = dinv[n] * (x[n] @ W)
// ---------------------------------------------------------------------------
__global__ __launch_bounds__(256) void xw_kernel(
    const float* __restrict__ x, const float* __restrict__ W,
    const float* __restrict__ dinv, float* __restrict__ xws, int N)
{
    __shared__ float sW[NODE_DIM * HID];   // 8 KB
    __shared__ float sx[64 * 129];         // ~33 KB
    const int t = threadIdx.x;

    #pragma unroll
    for (int i = 0; i < 8; ++i) sW[i * 256 + t] = W[i * 256 + t];

    const int base = blockIdx.x * 64;
    #pragma unroll
    for (int i = 0; i < 8; ++i) {
        int idx  = i * 256 + t;
        int row  = idx >> 5;
        int col4 = idx & 31;
        float4 v = make_float4(0.f, 0.f, 0.f, 0.f);
        int n = base + row;
        if (n < N) v = ((const float4*)x)[(size_t)n * 32 + col4];
        float* d = &sx[row * 129 + col4 * 4];
        d[0] = v.x; d[1] = v.y; d[2] = v.z; d[3] = v.w;
    }
    __syncthreads();

    #pragma unroll
    for (int o = 0; o < 4; ++o) {
        int out_idx = o * 256 + t;
        int row = out_idx >> 4, dim = out_idx & 15;
        const float* xr = &sx[row * 129];
        float acc = 0.f;
        #pragma unroll 4
        for (int k = 0; k < NODE_DIM; ++k) acc += xr[k] * sW[k * HID + dim];
        int n = base + row;
        if (n < N) xws[(size_t)n * HID + dim] = acc * dinv[n];
    }
}

// ---------------------------------------------------------------------------
// Per-bucket gather + self-loop + ReLU + mean-pool.
// 4 lanes per edge (float4 gather), unroll x4 -> 4 independent dwordx4 loads
// in flight per wave. LDS fp32 accumulation, no global float atomics.
// ---------------------------------------------------------------------------
__global__ __launch_bounds__(256) void gather_pool(
    const int* __restrict__ gOff, const int* __restrict__ ebuf,
    const float* __restrict__ dinv, const float* __restrict__ xws,
    const float* __restrict__ gcn_b, const int* __restrict__ batch,
    float* __restrict__ pool, float* __restrict__ cnt, int E, int N)
{
    __shared__ float acc[NPB * HID];     // 4 KB
    __shared__ float lpool[16 * HID];    // 1 KB
    __shared__ float lcnt[16];
    const int k = blockIdx.x, t = threadIdx.x;
    const int base = k << BSHIFT;

    for (int i = t; i < NPB * HID; i += 256) acc[i] = 0.f;
    if (t < 16 * HID) lpool[t] = 0.f;
    if (t < 16) lcnt[t] = 0.f;
    __syncthreads();

    int e0 = gOff[k * NBLK];
    int e1 = (k + 1 < NBUCK) ? gOff[(k + 1) * NBLK] : E;
    const int sub = t >> 2, q = t & 3;   // 64 edge-subgroups of 4 lanes
    const float4* xws4 = (const float4*)xws;

    int e = e0 + sub;
    for (; e + 192 < e1; e += 256) {
        int w0 = ebuf[e];
        int w1 = ebuf[e + 64];
        int w2 = ebuf[e + 128];
        int w3 = ebuf[e + 192];
        float4 v0 = xws4[(size_t)(w0 & 0x1FFFF) * 4 + q];
        float4 v1 = xws4[(size_t)(w1 & 0x1FFFF) * 4 + q];
        float4 v2 = xws4[(size_t)(w2 & 0x1FFFF) * 4 + q];
        float4 v3 = xws4[(size_t)(w3 & 0x1FFFF) * 4 + q];
        float* p0 = &acc[(w0 >> 17) * HID + q * 4];
        float* p1 = &acc[(w1 >> 17) * HID + q * 4];
        float* p2 = &acc[(w2 >> 17) * HID + q * 4];
        float* p3 = &acc[(w3 >> 17) * HID + q * 4];
        atomicAdd(p0+0, v0.x); atomicAdd(p0+1, v0.y); atomicAdd(p0+2, v0.z); atomicAdd(p0+3, v0.w);
        atomicAdd(p1+0, v1.x); atomicAdd(p1+1, v1.y); atomicAdd(p1+2, v1.z); atomicAdd(p1+3, v1.w);
        atomicAdd(p2+0, v2.x); atomicAdd(p2+1, v2.y); atomicAdd(p2+2, v2.z); atomicAdd(p2+3, v2.w);
        atomicAdd(p3+0, v3.x); atomicAdd(p3+1, v3.y); atomicAdd(p3+2, v3.z); atomicAdd(p3+3, v3.w);
    }
    for (; e < e1; e += 64) {
        int w = ebuf[e];
        float4 v = xws4[(size_t)(w & 0x1FFFF) * 4 + q];
        float* p = &acc[(w >> 17) * HID + q * 4];
        atomicAdd(p+0, v.x); atomicAdd(p+1, v.y); atomicAdd(p+2, v.z); atomicAdd(p+3, v.w);
    }
    __syncthreads();

    // epilogue: self-loop + bias + relu + pool (16-lane groups per node)
    int nN = min(NPB, N - base);
    int gmin = batch[base], gmax = batch[base + nN - 1];
    int range = gmax - gmin + 1;
    bool useL = (range <= 16);
    const int sub16 = t >> 4, lane = t & 15;
    float bb = gcn_b[lane];

    for (int i = sub16; i < nN; i += 16) {
        int n = base + i;
        float a = acc[i * HID + lane] + xws[(size_t)n * HID + lane];
        float r = fmaxf(fmaf(dinv[n], a, bb), 0.f);
        int g = batch[n];
        if (useL) {
            atomicAdd(&lpool[(g - gmin) * HID + lane], r);
            if (lane == 0) atomicAdd(&lcnt[g - gmin], 1.f);
        } else {
            atomicAdd(&pool[g * HID + lane], r);
            if (lane == 0) atomicAdd(&cnt[g], 1.f);
        }
    }
    __syncthreads();

    if (useL) {
        for (int i = t; i < range * HID; i += 256) {
            float v = lpool[i];
            if (v != 0.f) atomicAdd(&pool[gmin * HID + i], v);
        }
        for (int i = t; i < range; i += 256) {
            float c = lcnt[i];
            if (c != 0.f) atomicAdd(&cnt[gmin + i], c);
        }
    }
}

// ---------------------------------------------------------------------------
// Per-graph head: one wave per graph.
// ---------------------------------------------------------------------------
__global__ __launch_bounds__(64) void head_kernel(
    const float* __restrict__ pool, const float* __restrict__ cnt,
    const float* __restrict__ mri,  const float* __restrict__ cog,
    const float* __restrict__ clin, const float* __restrict__ gen,
    const float* __restrict__ mriW, const float* __restrict__ mrib,
    const float* __restrict__ cogW, const float* __restrict__ cogb,
    const float* __restrict__ clinW, const float* __restrict__ clinb,
    const float* __restrict__ genW, const float* __restrict__ genb,
    const float* __restrict__ W1, const float* __restrict__ b1,
    const float* __restrict__ W2, const float* __restrict__ b2,
    float* __restrict__ out)
{
    const int g = blockIdx.x;
    const int lane = threadIdx.x;
    __shared__ float comb[32];
    __shared__ float h[HID];

    if (lane < HID) {
        float c = fmaxf(cnt[g], 1.f);
        comb[lane] = pool[g * HID + lane] / c;
    }

    struct Mod { const float* in; const float* W; const float* b; int K; int off; };
    Mod mods[4] = {
        { mri  + (size_t)g * 256, mriW,  mrib,  256, 16 },
        { cog  + (size_t)g * 64,  cogW,  cogb,  64,  20 },
        { clin + (size_t)g * 32,  clinW, clinb, 32,  24 },
        { gen  + (size_t)g * 512, genW,  genb,  512, 28 },
    };
    for (int m = 0; m < 4; ++m) {
        float p0 = 0.f, p1 = 0.f, p2 = 0.f, p3 = 0.f;
        const float* in = mods[m].in;
        const float* Wm = mods[m].W;
        for (int kk = lane; kk < mods[m].K; kk += 64) {
            float xv = in[kk];
            p0 += xv * Wm[kk * 4 + 0];
            p1 += xv * Wm[kk * 4 + 1];
            p2 += xv * Wm[kk * 4 + 2];
            p3 += xv * Wm[kk * 4 + 3];
        }
        #pragma unroll
        for (int o = 32; o > 0; o >>= 1) {
            p0 += __shfl_down(p0, o);
            p1 += __shfl_down(p1, o);
            p2 += __shfl_down(p2, o);
            p3 += __shfl_down(p3, o);
        }
        if (lane == 0) {
            const float* bm = mods[m].b;
            int o = mods[m].off;
            comb[o + 0] = fmaxf(p0 + bm[0], 0.f);
            comb[o + 1] = fmaxf(p1 + bm[1], 0.f);
            comb[o + 2] = fmaxf(p2 + bm[2], 0.f);
            comb[o + 3] = fmaxf(p3 + bm[3], 0.f);
        }
    }
    __syncthreads();

    if (lane < HID) {
        float a = b1[lane];
        #pragma unroll
        for (int kk = 0; kk < 32; ++kk) a += comb[kk] * W1[kk * HID + lane];
        h[lane] = fmaxf(a, 0.f);
    }
    __syncthreads();

    if (lane == 0) {
        float l0 = b2[0], l1 = b2[1], l2 = b2[2];
        #pragma unroll
        for (int kk = 0; kk < HID; ++kk) {
            float hv = h[kk];
            l0 += hv * W2[kk * 3 + 0];
            l1 += hv * W2[kk * 3 + 1];
            l2 += hv * W2[kk * 3 + 2];
        }
        float mx = fmaxf(l0, fmaxf(l1, l2));
        float lse = mx + logf(expf(l0 - mx) + expf(l1 - mx) + expf(l2 - mx));
        out[g * 3 + 0] = l0 - lse;
        out[g * 3 + 1] = l1 - lse;
        out[g * 3 + 2] = l2 - lse;
    }
}

// ---------------------------------------------------------------------------
// Launch
// ---------------------------------------------------------------------------
extern "C" void kernel_launch(void* const* d_in, const int* in_sizes, int n_in,
                              void* d_out, int out_size, void* d_ws, size_t ws_size,
                              hipStream_t stream)
{
    const float* x     = (const float*)d_in[0];
    const int*   eidx  = (const int*)d_in[1];
    const int*   batch = (const int*)d_in[2];
    const float* mri   = (const float*)d_in[3];
    const float* cog   = (const float*)d_in[4];
    const float* clin  = (const float*)d_in[5];
    const float* gen   = (const float*)d_in[6];
    const float* gcn_W = (const float*)d_in[7];
    const float* gcn_b = (const float*)d_in[8];
    const float* mriW  = (const float*)d_in[9];
    const float* mrib  = (const float*)d_in[10];
    const float* cogW  = (const float*)d_in[11];
    const float* cogb  = (const float*)d_in[12];
    const float* clinW = (const float*)d_in[13];
    const float* clinb = (const float*)d_in[14];
    const float* genW  = (const float*)d_in[15];
    const float* genb  = (const float*)d_in[16];
    const float* W1    = (const float*)d_in[17];
    const float* b1    = (const float*)d_in[18];
    const float* W2    = (const float*)d_in[19];
    const float* b2    = (const float*)d_in[20];
    float* out = (float*)d_out;

    const int N = in_sizes[0] / NODE_DIM;   // 100000
    const int E = in_sizes[1] / 2;          // 3200000
    const int* src = eidx;
    const int* dst = eidx + E;

    // workspace layout (4-byte units)
    float* ws   = (float*)d_ws;
    float* xws  = ws;                        // 1,600,000 f
    float* dinv = ws + 1600000;              //   100,000 f
    float* pool = ws + 1700000;              //     4,096 f
    float* cnt  = ws + 1704096;              //       256 f
    int*   M    = (int*)(ws + 1705000);      //   400,128 i
    int*   bsum = (int*)(ws + 2105200);      //       256 i
    int*   ebuf = (int*)(ws + 2105712);      // 3,200,000 i
    // total ~5.31M * 4B = ~21.2 MB

    const int chunkE = (E + NBLK - 1) / NBLK;       // 12500
    const int scanNB = (TOT + 2047) / 2048;         // 196

    hipMemsetAsync(pool, 0, (N_GRAPHS * HID + N_GRAPHS) * sizeof(float), stream);

    bucket_count<<<NBLK, 256, 0, stream>>>(dst, M, E, chunkE);
    scan_blocksum<<<scanNB, 256, 0, stream>>>(M, bsum, TOT);
    scan_bsums<<<1, 256, 0, stream>>>(bsum, scanNB);
    scan_write<<<scanNB, 256, 0, stream>>>(M, bsum, TOT);
    bucket_scatter<<<NBLK, 256, 0, stream>>>(src, dst, M, ebuf, E, chunkE);
    deg_dinv<<<NBUCK, 256, 0, stream>>>(M, ebuf, dinv, E, N);
    xw_kernel<<<(N + 63) / 64, 256, 0, stream>>>(x, gcn_W, dinv, xws, N);
    gather_pool<<<NBUCK, 256, 0, stream>>>(M, ebuf, dinv, xws, gcn_b, batch,
                                           pool, cnt, E, N);
    head_kernel<<<N_GRAPHS, 64, 0, stream>>>(
        pool, cnt, mri, cog, clin, gen,
        mriW, mrib, cogW, cogb, clinW, clinb, genW, genb,
        W1, b1, W2, b2, out);
}